// Round 9
// baseline (125.694 us; speedup 1.0000x reference)
//
#include <hip/hip_runtime.h>
#include <hip/hip_bf16.h>

#define NROWS 131072
#define KIN   784
#define H1N   128
#define H2N   64
#define OUTN  10

// chunked weight layouts: w1c[kb][col][8] with kb = k/8  (k in [0,800))
#define W1C_ELEMS (100 * 128 * 8)   // 102400
#define W2C_ELEMS (16 * 64 * 8)     // 8192
#define W3_ELEMS  (16 * 64)         // 1024

typedef short s16x8 __attribute__((ext_vector_type(8)));
typedef float f32x4 __attribute__((ext_vector_type(4)));

typedef __hip_bfloat16 bf16;

static __device__ __forceinline__ short b2s(float f) {
    bf16 h = __float2bfloat16(f);
    return *reinterpret_cast<short*>(&h);
}

static __device__ __forceinline__ s16x8 cvt8(f32x4 a, f32x4 b) {
    s16x8 r;
    r[0] = b2s(a[0]); r[1] = b2s(a[1]); r[2] = b2s(a[2]); r[3] = b2s(a[3]);
    r[4] = b2s(b[0]); r[5] = b2s(b[1]); r[6] = b2s(b[2]); r[7] = b2s(b[3]);
    return r;
}

// async global -> LDS: 16B/lane, per-lane global addr, wave-uniform LDS base
static __device__ __forceinline__ void gl2lds16(const void* g, char* l) {
    __builtin_amdgcn_global_load_lds(
        (const __attribute__((address_space(1))) void*)g,
        (__attribute__((address_space(3))) void*)l, 16, 0, 0);
}

#define WAITV(N) do { asm volatile("s_waitcnt vmcnt(" #N ")" ::: "memory"); \
                      __builtin_amdgcn_sched_barrier(0); } while (0)
#define WAITL()  do { asm volatile("s_waitcnt lgkmcnt(0)" ::: "memory"); \
                      __builtin_amdgcn_sched_barrier(0); } while (0)

// ---------------- dequant: int4(int32) * f32 scale -> bf16 (chunked layouts) --
__global__ __launch_bounds__(256) void dequant_kernel(
    const int* __restrict__ w1q, const float* __restrict__ s1,
    const int* __restrict__ w2q, const float* __restrict__ s2,
    const int* __restrict__ w3q, const float* __restrict__ s3,
    bf16* __restrict__ w1c, bf16* __restrict__ w2c, bf16* __restrict__ w3d)
{
    const int total = W1C_ELEMS + W2C_ELEMS + W3_ELEMS;
    for (int i = blockIdx.x * blockDim.x + threadIdx.x; i < total;
         i += gridDim.x * blockDim.x) {
        if (i < W1C_ELEMS) {
            int kb = i >> 10, rem = i & 1023;
            int col = rem >> 3, j = rem & 7;
            int k = kb * 8 + j;
            float v = 0.0f;
            if (k < KIN) v = (float)w1q[col * KIN + k] * s1[col];
            w1c[i] = __float2bfloat16(v);
        } else if (i < W1C_ELEMS + W2C_ELEMS) {
            int t = i - W1C_ELEMS;
            int kb = t >> 9, rem = t & 511;
            int col = rem >> 3, j = rem & 7;
            int k = kb * 8 + j;
            w2c[t] = __float2bfloat16((float)w2q[col * H1N + k] * s2[col]);
        } else {
            int t = i - W1C_ELEMS - W2C_ELEMS;
            int r = t >> 6, c = t & 63;
            float v = 0.0f;
            if (r < OUTN) v = (float)w3q[r * H2N + c] * s3[r];
            w3d[t] = __float2bfloat16(v);
        }
    }
}

// ---------------- fused MLP ------------------------------------------------
// 256 threads (4 waves), BM=128, wave owns 32 rows. A(x) via a WAVE-PRIVATE
// 2-slot gl_lds ring (4KB slots); B(W1) direct VGPR loads from L2, issued
// BEFORE the A-issue each window so the compiler's pre-MFMA vmcnt(4) retires
// B(t) while leaving A(t+2) airborne. ZERO barriers. Arenas overlay the
// wave's own 8KB ring (XOR-swizzled h1/h2 to avoid padding). 4 blocks/CU,
// grid 1024 = one exact round.
__global__ __launch_bounds__(256, 4) void mlp_kernel(
    const float* __restrict__ x,
    const bf16*  __restrict__ w1c,
    const bf16*  __restrict__ w2c,
    const bf16*  __restrict__ w3d,
    const float* __restrict__ b1,
    const float* __restrict__ b2,
    const float* __restrict__ b3,
    float* __restrict__ out)
{
    __shared__ __align__(16) char lds[32768];   // wave wv: [wv*8KB, wv*8KB+8KB)

    const int tid  = threadIdx.x;
    const int lane = tid & 63;
    const int wv   = tid >> 6;
    const int r16  = lane & 15;
    const int kg   = lane >> 4;     // 0..3
    const int kgo  = kg * 8;

    const int i3 = lane >> 3;       // staging row-in-group 0..7
    const int i7 = lane & 7;        // staging LDS 16B-slot 0..7
    const int sw = i7 ^ (i3 & 7);   // swizzled global seg index
    const int adj = (sw >= 4) ? 16 : 0;   // tail-window redirect (stay in-row)

    const long long rowW = (long long)blockIdx.x * 128 + wv * 32;
    const float* gA = x + (rowW + i3) * (long long)KIN + sw * 4;
    char* ringw = lds + (wv << 13);

    // consume ds offsets (slot-relative): a0 = row r16, a1 = row 16+r16
    const int sw0 = ((2 * kg) ^ (r16 & 7)) * 16;
    const int sw1 = ((2 * kg + 1) ^ (r16 & 7)) * 16;
    const int aoff0 = r16 * 128 + sw0;          // +2048 for a1 rows
    const int aoff1 = r16 * 128 + sw1;

    // prologue: stage windows 0,1 into slots 0,1 (4 gl_lds each)
#pragma unroll
    for (int w = 0; w < 2; ++w) {
        char* sd = ringw + w * 4096;
#pragma unroll
        for (int j = 0; j < 4; ++j)
            gl2lds16(gA + j * (8 * KIN) + w * 32, sd + j * 1024);
    }

    f32x4 acc1[2][8];
#pragma unroll
    for (int i = 0; i < 2; ++i)
#pragma unroll
        for (int j = 0; j < 8; ++j) acc1[i][j] = (f32x4){0.f, 0.f, 0.f, 0.f};

    const bf16* bptr = w1c + (size_t)kg * 1024 + (size_t)r16 * 8;

#pragma unroll 1
    for (int t = 0; t < 24; ++t) {
        WAITV(4);                    // A(t) landed (A(t+1) may stay airborne)
        const char* sb = ringw + (t & 1) * 4096;
        f32x4 q00 = *(const f32x4*)(sb + aoff0);
        f32x4 q01 = *(const f32x4*)(sb + aoff1);
        f32x4 q10 = *(const f32x4*)(sb + aoff0 + 2048);
        f32x4 q11 = *(const f32x4*)(sb + aoff1 + 2048);

        // B(t): 8 direct loads (L2-hot), BEFORE the A-issue
        s16x8 bw[8];
#pragma unroll
        for (int nj = 0; nj < 8; ++nj) bw[nj] = *(const s16x8*)(bptr + nj * 128);

        WAITL();                     // q's in regs -> slot may be overwritten
        if (t < 22) {                // stage A(t+2) into this same slot
            char* sd = ringw + (t & 1) * 4096;
            const float* g = gA + (t + 2) * 32;
#pragma unroll
            for (int j = 0; j < 4; ++j)
                gl2lds16(g + j * (8 * KIN), sd + j * 1024);
        } else if (t == 22) {        // window 24: segs>=4 redirected in-row
            char* sd = ringw + (t & 1) * 4096;
            const float* g = gA + 768 - adj;
#pragma unroll
            for (int j = 0; j < 4; ++j)
                gl2lds16(g + j * (8 * KIN), sd + j * 1024);
        }

        s16x8 a0 = cvt8(q00, q01);
        s16x8 a1 = cvt8(q10, q11);
#pragma unroll
        for (int nj = 0; nj < 8; ++nj) {
            acc1[0][nj] = __builtin_amdgcn_mfma_f32_16x16x32_bf16(a0, bw[nj], acc1[0][nj], 0, 0, 0);
            acc1[1][nj] = __builtin_amdgcn_mfma_f32_16x16x32_bf16(a1, bw[nj], acc1[1][nj], 0, 0, 0);
        }
        bptr += 4096;
    }
    {   // window 24 (k 768..799; weights zero for k>=784, A staged at t=22)
        WAITV(0);
        const char* sb = ringw;      // slot 0
        f32x4 q00 = *(const f32x4*)(sb + aoff0);
        f32x4 q01 = *(const f32x4*)(sb + aoff1);
        f32x4 q10 = *(const f32x4*)(sb + aoff0 + 2048);
        f32x4 q11 = *(const f32x4*)(sb + aoff1 + 2048);
        s16x8 bw[8];
#pragma unroll
        for (int nj = 0; nj < 8; ++nj) bw[nj] = *(const s16x8*)(bptr + nj * 128);
        WAITL();
        s16x8 a0 = cvt8(q00, q01);
        s16x8 a1 = cvt8(q10, q11);
#pragma unroll
        for (int nj = 0; nj < 8; ++nj) {
            acc1[0][nj] = __builtin_amdgcn_mfma_f32_16x16x32_bf16(a0, bw[nj], acc1[0][nj], 0, 0, 0);
            acc1[1][nj] = __builtin_amdgcn_mfma_f32_16x16x32_bf16(a1, bw[nj], acc1[1][nj], 0, 0, 0);
        }
    }
    // wave's vmem fully retired (WAITV(0) + compiler B-drain) -> overlay safe.

    // ---- h1 arena in wave's own 8KB ring: [32 rows][128 cols] bf16,
    //      byte = row*256 + ((col*2) ^ ((row&7)<<4))  (XOR granule swizzle)
#pragma unroll
    for (int mi = 0; mi < 2; ++mi)
#pragma unroll
        for (int nj = 0; nj < 8; ++nj) {
            const int col = nj * 16 + r16;
            const float bb = b1[col];
#pragma unroll
            for (int r = 0; r < 4; ++r) {
                const int row = mi * 16 + kg * 4 + r;
                *(short*)(ringw + row * 256 + ((col * 2) ^ ((row & 7) << 4))) =
                    b2s(fmaxf(acc1[mi][nj][r] + bb, 0.0f));
            }
        }

    // ---- layer 2: [32 x 128] @ [128 x 64] per wave ----
    f32x4 acc2[2][4];
#pragma unroll
    for (int i = 0; i < 2; ++i)
#pragma unroll
        for (int j = 0; j < 4; ++j) acc2[i][j] = (f32x4){0.f, 0.f, 0.f, 0.f};

#pragma unroll
    for (int it = 0; it < 4; ++it) {
        const int kk2 = (it * 32 + kgo) * 2;
        s16x8 a0 = *(const s16x8*)(ringw + r16 * 256 + (kk2 ^ ((r16 & 7) << 4)));
        s16x8 a1 = *(const s16x8*)(ringw + (16 + r16) * 256 + (kk2 ^ ((r16 & 7) << 4)));
        const bf16* bp2 = w2c + (size_t)(it * 4 + kg) * 512 + (size_t)r16 * 8;
#pragma unroll
        for (int nj = 0; nj < 4; ++nj) {
            s16x8 b = *(const s16x8*)(bp2 + nj * 128);
            acc2[0][nj] = __builtin_amdgcn_mfma_f32_16x16x32_bf16(a0, b, acc2[0][nj], 0, 0, 0);
            acc2[1][nj] = __builtin_amdgcn_mfma_f32_16x16x32_bf16(a1, b, acc2[1][nj], 0, 0, 0);
        }
    }

    // ---- h2 arena overlay: [32][64] bf16, byte = row*128 + ((col*2)^((row&7)<<4))
#pragma unroll
    for (int mi = 0; mi < 2; ++mi)
#pragma unroll
        for (int nj = 0; nj < 4; ++nj) {
            const int col = nj * 16 + r16;
            const float bb = b2[col];
#pragma unroll
            for (int r = 0; r < 4; ++r) {
                const int row = mi * 16 + kg * 4 + r;
                *(short*)(ringw + row * 128 + ((col * 2) ^ ((row & 7) << 4))) =
                    b2s(fmaxf(acc2[mi][nj][r] + bb, 0.0f));
            }
        }

    // ---- layer 3: [32 x 64] @ [64 x 16] (rows 10..15 of W3 are zero) ----
    f32x4 acc3[2];
#pragma unroll
    for (int i = 0; i < 2; ++i) acc3[i] = (f32x4){0.f, 0.f, 0.f, 0.f};

#pragma unroll
    for (int it = 0; it < 2; ++it) {
        const int kk2 = (it * 32 + kgo) * 2;
        s16x8 a0 = *(const s16x8*)(ringw + r16 * 128 + (kk2 ^ ((r16 & 7) << 4)));
        s16x8 a1 = *(const s16x8*)(ringw + (16 + r16) * 128 + (kk2 ^ ((r16 & 7) << 4)));
        s16x8 b  = *(const s16x8*)(w3d + r16 * H2N + it * 32 + kgo);
        acc3[0] = __builtin_amdgcn_mfma_f32_16x16x32_bf16(a0, b, acc3[0], 0, 0, 0);
        acc3[1] = __builtin_amdgcn_mfma_f32_16x16x32_bf16(a1, b, acc3[1], 0, 0, 0);
    }

    // stage f32 outputs in the wave arena (plain layout), then write coalesced
    float* ob = (float*)ringw;   // 32*10 f32 = 1280 B
    const float bb3 = (r16 < OUTN) ? b3[r16] : 0.0f;
#pragma unroll
    for (int mi = 0; mi < 2; ++mi)
#pragma unroll
        for (int r = 0; r < 4; ++r) {
            const int row = mi * 16 + kg * 4 + r;
            if (r16 < OUTN) ob[row * OUTN + r16] = acc3[mi][r] + bb3;
        }
    const long long obase = rowW * OUTN;
    for (int i = lane; i < 32 * OUTN; i += 64) out[obase + i] = ob[i];
}

extern "C" void kernel_launch(void* const* d_in, const int* in_sizes, int n_in,
                              void* d_out, int out_size, void* d_ws, size_t ws_size,
                              hipStream_t stream) {
    const float* x   = (const float*)d_in[0];
    const int*   w1q = (const int*)d_in[1];
    const float* s1  = (const float*)d_in[2];
    const float* b1  = (const float*)d_in[3];
    const int*   w2q = (const int*)d_in[4];
    const float* s2  = (const float*)d_in[5];
    const float* b2  = (const float*)d_in[6];
    const int*   w3q = (const int*)d_in[7];
    const float* s3  = (const float*)d_in[8];
    const float* b3  = (const float*)d_in[9];
    float* out = (float*)d_out;

    bf16* w1c = (bf16*)d_ws;              // [100][128][8]
    bf16* w2c = w1c + W1C_ELEMS;          // [16][64][8]
    bf16* w3d = w2c + W2C_ELEMS;          // [16][64]

    dequant_kernel<<<128, 256, 0, stream>>>(w1q, s1, w2q, s2, w3q, s3, w1c, w2c, w3d);
    mlp_kernel<<<NROWS / 128, 256, 0, stream>>>(x, w1c, w2c, w3d, b1, b2, b3, out);
}